// Round 9
// baseline (150.233 us; speedup 1.0000x reference)
//
#include <hip/hip_runtime.h>
#include <math.h>
#include <stdint.h>

#define B_   4
#define C_   256
#define H_   64
#define W_   64
#define CC_  64
#define OE_  196
#define OH_  128
#define OW_  128

typedef uint32_t u32;
typedef unsigned short u16;
typedef __attribute__((ext_vector_type(8))) short bf16x8;
typedef __attribute__((ext_vector_type(4))) float f32x4;
typedef __attribute__((ext_vector_type(4))) u32 u32x4;
typedef __attribute__((ext_vector_type(2))) u32 u32x2;

__device__ __forceinline__ u16 f2bf(float f) {
  u32 u = __builtin_bit_cast(u32, f);
  u32 r = (u + 0x7FFFu + ((u >> 16) & 1u)) >> 16;   // RNE
  return (u16)r;
}

// ------------------------------------------------------------------
// Kernel 0: weight re-layouts (tiny).
//  wct[c][cc] = w_comp[cc][c]
//  wfrag[ks(50)][mt(14)][lane(64)][j(8)] bf16 fragment-linear A operand
// ------------------------------------------------------------------
__global__ __launch_bounds__(256) void prep_weights(
    const float* __restrict__ w_comp, const float* __restrict__ w_enc,
    float* __restrict__ wct, u16* __restrict__ wfrag) {
  int idx = blockIdx.x * 256 + threadIdx.x;
  if (idx < 50 * 14 * 64) {
    int lane = idx & 63;
    int mt   = (idx >> 6) % 14;
    int ks   = idx / (14 * 64);
    int o    = mt * 16 + (lane & 15);
    int tap  = ks >> 1, s = ks & 1;
    int ky   = tap / 5, kx = tap % 5;
    int cb   = s * 32 + (lane >> 4) * 8;
    u32 pk[4];
    #pragma unroll
    for (int p = 0; p < 4; ++p) {
      u16 lo = 0, hi = 0;
      if (o < OE_) {
        lo = f2bf(w_enc[((o * CC_ + cb + 2 * p) * 5 + ky) * 5 + kx]);
        hi = f2bf(w_enc[((o * CC_ + cb + 2 * p + 1) * 5 + ky) * 5 + kx]);
      }
      pk[p] = (u32)lo | ((u32)hi << 16);
    }
    *reinterpret_cast<u32x4*>(wfrag + (size_t)idx * 8) =
        *reinterpret_cast<u32x4*>(pk);
  }
  if (idx < C_ * CC_) {
    int cc = idx / C_, c = idx % C_;
    wct[c * CC_ + cc] = w_comp[cc * C_ + c];
  }
}

// ------------------------------------------------------------------
// Kernel 1: 1x1 compressor — 16-w blocks, grid 1024, LDS 20KB.
// ------------------------------------------------------------------
__global__ __launch_bounds__(256) void compress_k(
    const float* __restrict__ x, const float* __restrict__ wct,
    const float* __restrict__ b_comp, u16* __restrict__ comp) {
  __shared__ float xs[C_ * 20];   // 20,480B
  int t   = threadIdx.x;
  int gid = blockIdx.x;           // bh*4 + wq
  int wq  = gid & 3;
  int bh  = gid >> 2;
  int b = bh >> 6, h = bh & 63;
  int w0 = wq * 16;

  const float* xrow = x + (size_t)b * C_ * H_ * W_ + (size_t)h * W_ + w0;
  for (int i = t; i < 1024; i += 256) {    // 256 c x 4 f32x4
    int c = i >> 2, q = i & 3;
    f32x4 v = *reinterpret_cast<const f32x4*>(xrow + (size_t)c * H_ * W_ + q * 4);
    *reinterpret_cast<f32x4*>(xs + c * 20 + q * 4) = v;
  }
  __syncthreads();

  int w = t & 15, cq = t >> 4;   // cq 0..15 -> 4 cc each
  float acc[4] = {0.f, 0.f, 0.f, 0.f};
  for (int c = 0; c < C_; ++c) {
    float xv = xs[c * 20 + w];
    const float* wr = wct + c * CC_ + cq * 4;
    #pragma unroll
    for (int i = 0; i < 4; ++i) acc[i] = fmaf(xv, wr[i], acc[i]);
  }
  u32 pk[2];
  #pragma unroll
  for (int p = 0; p < 2; ++p) {
    u16 lo = f2bf(acc[2 * p]     + b_comp[cq * 4 + 2 * p]);
    u16 hi = f2bf(acc[2 * p + 1] + b_comp[cq * 4 + 2 * p + 1]);
    pk[p] = (u32)lo | ((u32)hi << 16);
  }
  *reinterpret_cast<u32x2*>(comp + ((size_t)bh * 64 + w0 + w) * CC_ + cq * 4) =
      *reinterpret_cast<u32x2*>(pk);
}

// ------------------------------------------------------------------
// Kernel 2: encoder MFMA GEMM v5 — N-split (unchanged from R8).
// ------------------------------------------------------------------
#define ELG_ 32256   // 224*36*4

__device__ __forceinline__ void enc_lda(
    bf16x8 (&a)[4], const u16* __restrict__ wfrag,
    int ks, int mtbase, int mtcnt, int lane) {
  #pragma unroll
  for (int mm = 0; mm < 4; ++mm)
    if (mm < mtcnt)
      a[mm] = *reinterpret_cast<const bf16x8*>(
          wfrag + (((size_t)ks * 14 + mtbase + mm) * 64 + lane) * 8);
}

__device__ __forceinline__ void enc_step(
    int ks, const char* lds, const bf16x8 (&a)[4], f32x4 (&acc)[4][2],
    int nlane, int kq, int mtcnt) {
  int tap = ks >> 1, s = ks & 1;
  int ky = tap / 5, kx = tap % 5;
  bf16x8 bf[2];
  #pragma unroll
  for (int nt = 0; nt < 2; ++nt) {
    int col = nt * 16 + nlane + kx;
    int byte = (((ky * 36 + col) * 64 + s * 32 + kq * 8) * 2) ^ ((col & 7) << 4);
    bf[nt] = *reinterpret_cast<const bf16x8*>(lds + byte);
  }
  #pragma unroll
  for (int mm = 0; mm < 4; ++mm) {
    if (mm < mtcnt) {
      #pragma unroll
      for (int nt = 0; nt < 2; ++nt)
        acc[mm][nt] = __builtin_amdgcn_mfma_f32_16x16x32_bf16(
            a[mm], bf[nt], acc[mm][nt], 0, 0, 0);
    }
  }
}

__global__ __launch_bounds__(256) void enc_mfma_k(
    const u16* __restrict__ comp, const u16* __restrict__ wfrag,
    const float* __restrict__ b_enc, float* __restrict__ smax) {
  __shared__ __align__(16) char lds[ELG_];

  int t   = threadIdx.x;
  int bid = blockIdx.x;
  int swz = (bid & 7) * 64 + (bid >> 3);   // 512 blocks, bijective
  int wh  = swz & 1;
  int bh  = swz >> 1;
  int b = bh >> 6, h = bh & 63;
  int w0 = wh * 32;

  // ---- stage B tile: 5 rows x 36 cols (gw = w0-2+col) x 64 ch ----
  {
    const u16* cbse = comp + (size_t)b * H_ * W_ * CC_;
    for (int i = t; i < 1440; i += 256) {
      int q = i & 7, colr = i >> 3;
      int col = colr % 36, r = colr / 36;
      int hh = h - 2 + r, gw = w0 - 2 + col;
      u32x4 v = {0, 0, 0, 0};
      if ((unsigned)hh < H_ && (unsigned)gw < W_)
        v = *reinterpret_cast<const u32x4*>(cbse + ((size_t)hh * W_ + gw) * CC_ + q * 8);
      int byte = ((r * 36 + col) * 128 + q * 16) ^ ((col & 7) << 4);
      *reinterpret_cast<u32x4*>(lds + byte) = v;
    }
  }
  __syncthreads();   // B ready; no further barriers in K-loop

  int wv    = __builtin_amdgcn_readfirstlane(t >> 6);
  int lane  = t & 63;
  int nlane = lane & 15, kq = lane >> 4;
  int mtbase = (wv < 2) ? wv * 4 : 3 * wv + 2;   // {0,4,8,11}
  int mtcnt  = (wv < 2) ? 4 : 3;

  f32x4 acc[4][2];
  #pragma unroll
  for (int mm = 0; mm < 4; ++mm)
    #pragma unroll
    for (int nt = 0; nt < 2; ++nt) acc[mm][nt] = (f32x4){0.f, 0.f, 0.f, 0.f};

  bf16x8 aA[4], aB[4];
  enc_lda(aA, wfrag, 0, mtbase, mtcnt, lane);
  enc_lda(aB, wfrag, 1, mtbase, mtcnt, lane);
  for (int ks = 0; ks + 2 < 50; ks += 2) {
    enc_step(ks, lds, aA, acc, nlane, kq, mtcnt);
    enc_lda(aA, wfrag, ks + 2, mtbase, mtcnt, lane);
    enc_step(ks + 1, lds, aB, acc, nlane, kq, mtcnt);
    enc_lda(aB, wfrag, ks + 3, mtbase, mtcnt, lane);
  }
  enc_step(48, lds, aA, acc, nlane, kq, mtcnt);
  enc_step(49, lds, aB, acc, nlane, kq, mtcnt);

  // ---- epilogue: logits -> LDS [224][36] f32, fused softmax ----
  __syncthreads();
  float* lg = (float*)lds;
  #pragma unroll
  for (int mm = 0; mm < 4; ++mm) {
    if (mm < mtcnt) {
      #pragma unroll
      for (int nt = 0; nt < 2; ++nt) {
        #pragma unroll
        for (int r = 0; r < 4; ++r) {
          int m  = (mtbase + mm) * 16 + kq * 4 + r;
          int px = nt * 16 + nlane;
          lg[m * 36 + px] = acc[mm][nt][r] + (m < OE_ ? b_enc[m] : 0.f);
        }
      }
    }
  }
  __syncthreads();

  if (t < 128) {
    int px = t & 31, rr = t >> 5;   // rr 0..3
    float v[49];
    float mx = -1e30f;
    #pragma unroll
    for (int n = 0; n < 49; ++n) {
      v[n] = lg[(4 * n + rr) * 36 + px];
      mx = fmaxf(mx, v[n]);
    }
    float sum = 0.f;
    #pragma unroll
    for (int n = 0; n < 49; ++n) { v[n] = __expf(v[n] - mx); sum += v[n]; }
    float inv = 1.f / sum;
    float* so = smax + ((size_t)bh * 64 + w0 + px) * OE_;
    #pragma unroll
    for (int n = 0; n < 49; ++n) so[n * 4 + rr] = v[n] * inv;   // [n][r]
  }
}

// ------------------------------------------------------------------
// Kernel 3: CARAFE v9 — R8 structure (0-conflict staging, XCD swizzle,
// direct-x) + 7-deep svA/svB dy-pipeline WITH register headroom:
// __launch_bounds__(256,2) allows ~92-128 VGPR (acc16+svA28+svB28+misc)
// without spilling, while LDS 38.4KB still permits 4 blocks/CU.
// ------------------------------------------------------------------
__global__ __launch_bounds__(256, 2) void carafe_k(
    const float* __restrict__ x, const float* __restrict__ smax,
    float* __restrict__ out) {
  __shared__ __align__(16) float xs[7 * 38 * 36];   // 38,304 B
  int t   = threadIdx.x;
  int bid = blockIdx.x;
  int swz = (bid & 7) * 512 + (bid >> 3);   // 4096 blocks, bijective
  int cg  = swz & 7;
  int wh  = (swz >> 3) & 1;
  int bh  = swz >> 4;
  int b = bh >> 6, h = bh & 63;
  int c0 = cg * 32, w0 = wh * 32;

  int w = t & 31;
  int coff = (t >> 5) * 4;
  const float* sp = smax + ((size_t)bh * 64 + w0 + w) * OE_;

  // dy=0 sv preload: independent of LDS, overlaps staging
  f32x4 svA[7], svB[7];
  #pragma unroll
  for (int n = 0; n < 7; ++n)
    svA[n] = *reinterpret_cast<const f32x4*>(sp + n * 4);

  // ---- stage x tile: thread = (dy, j, cq): 4 scalar loads + 1 b128 write
  const float* xb = x + (size_t)(b * C_ + c0) * H_ * W_;
  for (int idx = t; idx < 2128; idx += 256) {
    int cq = idx & 7, rj = idx >> 3;       // rj = dy*38 + j
    int dy = rj / 38, j = rj - dy * 38;
    int gh = h - 3 + dy, gw = w0 - 3 + j;
    f32x4 v = {0.f, 0.f, 0.f, 0.f};
    if ((unsigned)gh < H_ && (unsigned)gw < W_) {
      const float* xp = xb + (size_t)(cq * 4) * H_ * W_ + gh * W_ + gw;
      v[0] = xp[0];
      v[1] = xp[H_ * W_];
      v[2] = xp[2 * H_ * W_];
      v[3] = xp[3 * H_ * W_];
    }
    *reinterpret_cast<f32x4*>(xs + rj * 36 + cq * 4) = v;
  }
  __syncthreads();

  f32x4 acc[4];
  #pragma unroll
  for (int ci = 0; ci < 4; ++ci) acc[ci] = (f32x4){0.f, 0.f, 0.f, 0.f};

  #pragma unroll
  for (int dy = 0; dy < 7; ++dy) {
    if (dy < 6) {   // prefetch dy+1's 7 sv into the spare buffer
      #pragma unroll
      for (int n = 0; n < 7; ++n) {
        f32x4 v = *reinterpret_cast<const f32x4*>(sp + ((dy + 1) * 7 + n) * 4);
        if (dy & 1) svA[n] = v; else svB[n] = v;   // static after unroll
      }
    }
    #pragma unroll
    for (int dx = 0; dx < 7; ++dx) {
      f32x4 sv = (dy & 1) ? svB[dx] : svA[dx];
      f32x4 xv = *reinterpret_cast<const f32x4*>(
          xs + (dy * 38 + w + dx) * 36 + coff);
      #pragma unroll
      for (int ci = 0; ci < 4; ++ci) {
        acc[ci][0] = fmaf(xv[ci], sv[0], acc[ci][0]);
        acc[ci][1] = fmaf(xv[ci], sv[1], acc[ci][1]);
        acc[ci][2] = fmaf(xv[ci], sv[2], acc[ci][2]);
        acc[ci][3] = fmaf(xv[ci], sv[3], acc[ci][3]);
      }
    }
  }
  #pragma unroll
  for (int ci = 0; ci < 4; ++ci) {
    int c = c0 + coff + ci;
    float* base = out + ((size_t)(b * C_ + c) * OH_ + 2 * h) * OW_ + 2 * (w0 + w);
    *reinterpret_cast<float2*>(base)       = make_float2(acc[ci][0], acc[ci][1]);
    *reinterpret_cast<float2*>(base + OW_) = make_float2(acc[ci][2], acc[ci][3]);
  }
}

// ------------------------------------------------------------------
extern "C" void kernel_launch(void* const* d_in, const int* in_sizes, int n_in,
                              void* d_out, int out_size, void* d_ws, size_t ws_size,
                              hipStream_t stream) {
  const float* x      = (const float*)d_in[0];
  const float* w_comp = (const float*)d_in[1];
  const float* b_comp = (const float*)d_in[2];
  const float* w_enc  = (const float*)d_in[3];
  const float* b_enc  = (const float*)d_in[4];
  float* out = (float*)d_out;

  float* ws = (float*)d_ws;
  float* smax = ws;                             // 3,211,264 f32
  float* wct  = ws + 3211264;                   //    16,384 f32
  u16* wfrag  = (u16*)(wct + 16384);            //   358,400 bf16
  u16* comp   = wfrag + 358400;                 // 1,048,576 bf16

  prep_weights<<<175, 256, 0, stream>>>(w_comp, w_enc, wct, wfrag);
  compress_k<<<B_ * H_ * 4, 256, 0, stream>>>(x, wct, b_comp, comp);
  enc_mfma_k<<<512, 256, 0, stream>>>(comp, wfrag, b_enc, smax);
  carafe_k<<<B_ * H_ * 2 * 8, 256, 0, stream>>>(x, smax, out);
}

// Round 10
// 142.507 us; speedup vs baseline: 1.0542x; 1.0542x over previous
//
#include <hip/hip_runtime.h>
#include <math.h>
#include <stdint.h>

#define B_   4
#define C_   256
#define H_   64
#define W_   64
#define CC_  64
#define OE_  196
#define OH_  128
#define OW_  128

typedef uint32_t u32;
typedef unsigned short u16;
typedef __attribute__((ext_vector_type(8))) short bf16x8;
typedef __attribute__((ext_vector_type(4))) float f32x4;
typedef __attribute__((ext_vector_type(4))) u32 u32x4;
typedef __attribute__((ext_vector_type(2))) u32 u32x2;

__device__ __forceinline__ u16 f2bf(float f) {
  u32 u = __builtin_bit_cast(u32, f);
  u32 r = (u + 0x7FFFu + ((u >> 16) & 1u)) >> 16;   // RNE
  return (u16)r;
}

// ------------------------------------------------------------------
// Kernel 0: weight re-layouts (tiny).
// ------------------------------------------------------------------
__global__ __launch_bounds__(256) void prep_weights(
    const float* __restrict__ w_comp, const float* __restrict__ w_enc,
    float* __restrict__ wct, u16* __restrict__ wfrag) {
  int idx = blockIdx.x * 256 + threadIdx.x;
  if (idx < 50 * 14 * 64) {
    int lane = idx & 63;
    int mt   = (idx >> 6) % 14;
    int ks   = idx / (14 * 64);
    int o    = mt * 16 + (lane & 15);
    int tap  = ks >> 1, s = ks & 1;
    int ky   = tap / 5, kx = tap % 5;
    int cb   = s * 32 + (lane >> 4) * 8;
    u32 pk[4];
    #pragma unroll
    for (int p = 0; p < 4; ++p) {
      u16 lo = 0, hi = 0;
      if (o < OE_) {
        lo = f2bf(w_enc[((o * CC_ + cb + 2 * p) * 5 + ky) * 5 + kx]);
        hi = f2bf(w_enc[((o * CC_ + cb + 2 * p + 1) * 5 + ky) * 5 + kx]);
      }
      pk[p] = (u32)lo | ((u32)hi << 16);
    }
    *reinterpret_cast<u32x4*>(wfrag + (size_t)idx * 8) =
        *reinterpret_cast<u32x4*>(pk);
  }
  if (idx < C_ * CC_) {
    int cc = idx / C_, c = idx % C_;
    wct[c * CC_ + cc] = w_comp[cc * C_ + c];
  }
}

// ------------------------------------------------------------------
// Kernel 1: 1x1 compressor — 16-w blocks, grid 1024, LDS 20KB.
// ------------------------------------------------------------------
__global__ __launch_bounds__(256) void compress_k(
    const float* __restrict__ x, const float* __restrict__ wct,
    const float* __restrict__ b_comp, u16* __restrict__ comp) {
  __shared__ float xs[C_ * 20];
  int t   = threadIdx.x;
  int gid = blockIdx.x;
  int wq  = gid & 3;
  int bh  = gid >> 2;
  int b = bh >> 6, h = bh & 63;
  int w0 = wq * 16;

  const float* xrow = x + (size_t)b * C_ * H_ * W_ + (size_t)h * W_ + w0;
  for (int i = t; i < 1024; i += 256) {
    int c = i >> 2, q = i & 3;
    f32x4 v = *reinterpret_cast<const f32x4*>(xrow + (size_t)c * H_ * W_ + q * 4);
    *reinterpret_cast<f32x4*>(xs + c * 20 + q * 4) = v;
  }
  __syncthreads();

  int w = t & 15, cq = t >> 4;
  float acc[4] = {0.f, 0.f, 0.f, 0.f};
  for (int c = 0; c < C_; ++c) {
    float xv = xs[c * 20 + w];
    const float* wr = wct + c * CC_ + cq * 4;
    #pragma unroll
    for (int i = 0; i < 4; ++i) acc[i] = fmaf(xv, wr[i], acc[i]);
  }
  u32 pk[2];
  #pragma unroll
  for (int p = 0; p < 2; ++p) {
    u16 lo = f2bf(acc[2 * p]     + b_comp[cq * 4 + 2 * p]);
    u16 hi = f2bf(acc[2 * p + 1] + b_comp[cq * 4 + 2 * p + 1]);
    pk[p] = (u32)lo | ((u32)hi << 16);
  }
  *reinterpret_cast<u32x2*>(comp + ((size_t)bh * 64 + w0 + w) * CC_ + cq * 4) =
      *reinterpret_cast<u32x2*>(pk);
}

// ------------------------------------------------------------------
// Kernel 2: encoder MFMA GEMM v6 — N=32 split (occupancy) + A operand
// via global_load_lds double-buffer (R2-proven; 14 VMEM instr/ks/block
// instead of 1024).  LDS: B 23,040 + 2x14,336 = 51,712B; logits
// (32,256B) overlay after K-loop.  3 blocks/CU.
// ------------------------------------------------------------------
#define WB_ 14336
#define BT_ 23040

__device__ __forceinline__ void enc_step(
    int ks, const char* ldsb, const char* cur, f32x4 (&acc)[4][2],
    int nlane, int kq, int lane, int mtbase, int mtcnt) {
  int tap = ks >> 1, s = ks & 1;
  int ky = tap / 5, kx = tap % 5;
  bf16x8 bf[2];
  #pragma unroll
  for (int nt = 0; nt < 2; ++nt) {
    int col = nt * 16 + nlane + kx;
    int byte = (((ky * 36 + col) * 64 + s * 32 + kq * 8) * 2) ^ ((col & 7) << 4);
    bf[nt] = *reinterpret_cast<const bf16x8*>(ldsb + byte);
  }
  #pragma unroll
  for (int mm = 0; mm < 4; ++mm) {
    if (mm < mtcnt) {
      bf16x8 af = *reinterpret_cast<const bf16x8*>(
          cur + ((mtbase + mm) * 64 + lane) * 16);
      #pragma unroll
      for (int nt = 0; nt < 2; ++nt)
        acc[mm][nt] = __builtin_amdgcn_mfma_f32_16x16x32_bf16(
            af, bf[nt], acc[mm][nt], 0, 0, 0);
    }
  }
}

__global__ __launch_bounds__(256) void enc_mfma_k(
    const u16* __restrict__ comp, const u16* __restrict__ wfrag,
    const float* __restrict__ b_enc, float* __restrict__ smax) {
  __shared__ __align__(16) char lds[BT_ + 2 * WB_];   // 51,712B
  char* wbuf0 = lds + BT_;
  char* wbuf1 = lds + BT_ + WB_;

  int t   = threadIdx.x;
  int bid = blockIdx.x;
  int swz = (bid & 7) * 64 + (bid >> 3);   // 512 blocks, bijective
  int wh  = swz & 1;
  int bh  = swz >> 1;
  int b = bh >> 6, h = bh & 63;
  int w0 = wh * 32;

  int wv    = __builtin_amdgcn_readfirstlane(t >> 6);
  int lane  = t & 63;
  int nlane = lane & 15, kq = lane >> 4;
  int mtbase = (wv < 2) ? wv * 4 : 3 * wv + 2;   // {0,4,8,11}
  int mtcnt  = (wv < 2) ? 4 : 3;

  #define STAGE_W(ks, dstbuf)                                                 \
    {                                                                         \
      const char* _s = (const char*)wfrag + (size_t)(ks) * WB_;               \
      for (int _i = wv; _i < 14; _i += 4)                                     \
        __builtin_amdgcn_global_load_lds(                                     \
            (const __attribute__((address_space(1))) u32*)(_s + _i * 1024 +   \
                                                           lane * 16),        \
            (__attribute__((address_space(3))) u32*)((dstbuf) + _i * 1024),   \
            16, 0, 0);                                                        \
    }

  // ---- stage B tile: 5 rows x 36 cols x 64 ch, XOR-swizzled ----
  {
    const u16* cbse = comp + (size_t)b * H_ * W_ * CC_;
    for (int i = t; i < 1440; i += 256) {
      int q = i & 7, colr = i >> 3;
      int col = colr % 36, r = colr / 36;
      int hh = h - 2 + r, gw = w0 - 2 + col;
      u32x4 v = {0, 0, 0, 0};
      if ((unsigned)hh < H_ && (unsigned)gw < W_)
        v = *reinterpret_cast<const u32x4*>(cbse + ((size_t)hh * W_ + gw) * CC_ + q * 8);
      int byte = ((r * 36 + col) * 128 + q * 16) ^ ((col & 7) << 4);
      *reinterpret_cast<u32x4*>(lds + byte) = v;
    }
  }
  STAGE_W(0, wbuf0);
  __syncthreads();   // B + wbuf0 ready

  f32x4 acc[4][2];
  #pragma unroll
  for (int mm = 0; mm < 4; ++mm)
    #pragma unroll
    for (int nt = 0; nt < 2; ++nt) acc[mm][nt] = (f32x4){0.f, 0.f, 0.f, 0.f};

  for (int ks = 0; ks < 50; ++ks) {
    char* cur = (ks & 1) ? wbuf1 : wbuf0;
    char* nxt = (ks & 1) ? wbuf0 : wbuf1;
    if (ks + 1 < 50) STAGE_W(ks + 1, nxt);
    enc_step(ks, lds, cur, acc, nlane, kq, lane, mtbase, mtcnt);
    __syncthreads();
  }

  // ---- epilogue: logits overlay -> fused softmax ----
  float* lg = (float*)lds;
  #pragma unroll
  for (int mm = 0; mm < 4; ++mm) {
    if (mm < mtcnt) {
      #pragma unroll
      for (int nt = 0; nt < 2; ++nt) {
        #pragma unroll
        for (int r = 0; r < 4; ++r) {
          int m  = (mtbase + mm) * 16 + kq * 4 + r;
          int px = nt * 16 + nlane;
          lg[m * 36 + px] = acc[mm][nt][r] + (m < OE_ ? b_enc[m] : 0.f);
        }
      }
    }
  }
  __syncthreads();

  if (t < 128) {
    int px = t & 31, rr = t >> 5;
    float v[49];
    float mx = -1e30f;
    #pragma unroll
    for (int n = 0; n < 49; ++n) {
      v[n] = lg[(4 * n + rr) * 36 + px];
      mx = fmaxf(mx, v[n]);
    }
    float sum = 0.f;
    #pragma unroll
    for (int n = 0; n < 49; ++n) { v[n] = __expf(v[n] - mx); sum += v[n]; }
    float inv = 1.f / sum;
    float* so = smax + ((size_t)bh * 64 + w0 + px) * OE_;
    #pragma unroll
    for (int n = 0; n < 49; ++n) so[n * 4 + rr] = v[n] * inv;   // [n][r]
  }
}

// ------------------------------------------------------------------
// Kernel 3: CARAFE v10 — VMEM-instruction-minimized.
// Block = (b, 8 h-rows, 16 w, 32 ch): kills 7x h-halo staging
// redundancy.  xs channel-major [32][14][22] (39.4KB) staged once;
// ssm[16][212] (13.6KB) re-staged per h-step from smax (LDS sv
// broadcast replaces 49 global loads/thread).  Thread = (w-pair,
// channel): register j-window via 4xb64/dy, 2 b128 sv/tap, 8 FMA,
// f32x4 stores.  LDS 52,992B -> 3 blocks/CU.
// ------------------------------------------------------------------
__global__ __launch_bounds__(256) void carafe_k(
    const float* __restrict__ x, const float* __restrict__ smax,
    float* __restrict__ out) {
  __shared__ __align__(16) float xs[32 * 308];    // [c][14 rows][22 j]
  __shared__ __align__(16) float ssm[16 * 212];   // [w][196 pad 212]
  int t   = threadIdx.x;
  int bid = blockIdx.x;
  int swz = (bid & 7) * 128 + (bid >> 3);   // 1024 blocks, bijective
  int cg  = swz & 7;
  int wq  = (swz >> 3) & 3;
  int hg  = (swz >> 5) & 7;
  int b   = swz >> 8;
  int c0 = cg * 32, w0 = wq * 16, h0 = hg * 8;

  // ---- stage x tile once: 32 ch x 14 rows x 22 j ----
  const float* xb = x + (size_t)(b * C_ + c0) * H_ * W_;
  for (int idx = t; idx < 2688; idx += 256) {
    int c    = idx & 31;
    int rest = idx >> 5;            // 0..83
    int dy   = rest % 14, wv = rest / 14;   // wv 0..5
    int gh   = h0 - 3 + dy;
    int gw0  = w0 - 4 + wv * 4;     // 4-aligned
    f32x4 v = {0.f, 0.f, 0.f, 0.f};
    if ((unsigned)gh < H_ && (unsigned)gw0 < 61)
      v = *reinterpret_cast<const f32x4*>(xb + (size_t)c * H_ * W_ + gh * W_ + gw0);
    int jb = wv * 4 - 1;
    float* xr = xs + c * 308 + dy * 22;
    #pragma unroll
    for (int e = 0; e < 4; ++e) {
      int j = jb + e;
      if ((unsigned)j < 22) xr[j] = v[e];
    }
  }
  // ---- stage ssm for hs=0 ----
  {
    const float* sb = smax + ((size_t)((b * 64 + h0) * 64 + w0)) * OE_;
    for (int idx = t; idx < 784; idx += 256) {
      int w = idx / 49, n = idx - w * 49;
      f32x4 v = *reinterpret_cast<const f32x4*>(sb + (size_t)w * OE_ + n * 4);
      *reinterpret_cast<f32x4*>(ssm + w * 212 + n * 4) = v;
    }
  }
  __syncthreads();

  int wp = t & 7;        // w-pair: w = 2wp, 2wp+1
  int cq = t >> 3;       // 0..31 channel
  const float* xcrow = xs + cq * 308;
  int c  = c0 + cq;
  int wg = w0 + 2 * wp;

  for (int hs = 0; hs < 8; ++hs) {
    int h = h0 + hs;
    const float* s0 = ssm + (2 * wp) * 212;
    const float* s1 = s0 + 212;
    f32x4 accA = {0.f, 0.f, 0.f, 0.f};   // w = 2wp
    f32x4 accB = {0.f, 0.f, 0.f, 0.f};   // w = 2wp+1

    #pragma unroll
    for (int dy = 0; dy < 7; ++dy) {
      const float* xr = xcrow + (hs + dy) * 22 + 2 * wp;
      float2 q0 = *reinterpret_cast<const float2*>(xr);
      float2 q1 = *reinterpret_cast<const float2*>(xr + 2);
      float2 q2 = *reinterpret_cast<const float2*>(xr + 4);
      float2 q3 = *reinterpret_cast<const float2*>(xr + 6);
      float xw[8] = {q0.x, q0.y, q1.x, q1.y, q2.x, q2.y, q3.x, q3.y};
      #pragma unroll
      for (int dx = 0; dx < 7; ++dx) {
        int n = dy * 7 + dx;
        f32x4 svA = *reinterpret_cast<const f32x4*>(s0 + n * 4);
        f32x4 svB = *reinterpret_cast<const f32x4*>(s1 + n * 4);
        float xa = xw[dx];
        float xb2 = xw[dx + 1];
        accA[0] = fmaf(xa, svA[0], accA[0]);
        accA[1] = fmaf(xa, svA[1], accA[1]);
        accA[2] = fmaf(xa, svA[2], accA[2]);
        accA[3] = fmaf(xa, svA[3], accA[3]);
        accB[0] = fmaf(xb2, svB[0], accB[0]);
        accB[1] = fmaf(xb2, svB[1], accB[1]);
        accB[2] = fmaf(xb2, svB[2], accB[2]);
        accB[3] = fmaf(xb2, svB[3], accB[3]);
      }
    }

    float* base = out + ((size_t)(b * C_ + c) * OH_ + 2 * h) * OW_ + 2 * wg;
    f32x4 r0 = {accA[0], accA[1], accB[0], accB[1]};
    f32x4 r1 = {accA[2], accA[3], accB[2], accB[3]};
    *reinterpret_cast<f32x4*>(base)       = r0;
    *reinterpret_cast<f32x4*>(base + OW_) = r1;

    __syncthreads();   // all reads of ssm done
    if (hs < 7) {
      const float* sb = smax + ((size_t)((b * 64 + h0 + hs + 1) * 64 + w0)) * OE_;
      for (int idx = t; idx < 784; idx += 256) {
        int w = idx / 49, n = idx - w * 49;
        f32x4 v = *reinterpret_cast<const f32x4*>(sb + (size_t)w * OE_ + n * 4);
        *reinterpret_cast<f32x4*>(ssm + w * 212 + n * 4) = v;
      }
      __syncthreads();   // ssm writes visible
    }
  }
}

// ------------------------------------------------------------------
extern "C" void kernel_launch(void* const* d_in, const int* in_sizes, int n_in,
                              void* d_out, int out_size, void* d_ws, size_t ws_size,
                              hipStream_t stream) {
  const float* x      = (const float*)d_in[0];
  const float* w_comp = (const float*)d_in[1];
  const float* b_comp = (const float*)d_in[2];
  const float* w_enc  = (const float*)d_in[3];
  const float* b_enc  = (const float*)d_in[4];
  float* out = (float*)d_out;

  float* ws = (float*)d_ws;
  float* smax = ws;                             // 3,211,264 f32
  float* wct  = ws + 3211264;                   //    16,384 f32
  u16* wfrag  = (u16*)(wct + 16384);            //   358,400 bf16
  u16* comp   = wfrag + 358400;                 // 1,048,576 bf16

  prep_weights<<<175, 256, 0, stream>>>(w_comp, w_enc, wct, wfrag);
  compress_k<<<B_ * H_ * 4, 256, 0, stream>>>(x, wct, b_comp, comp);
  enc_mfma_k<<<512, 256, 0, stream>>>(comp, wfrag, b_enc, smax);
  carafe_k<<<1024, 256, 0, stream>>>(x, smax, out);
}

// Round 11
// 122.101 us; speedup vs baseline: 1.2304x; 1.1671x over previous
//
#include <hip/hip_runtime.h>
#include <math.h>
#include <stdint.h>

#define B_   4
#define C_   256
#define H_   64
#define W_   64
#define CC_  64
#define OE_  196
#define OH_  128
#define OW_  128

typedef uint32_t u32;
typedef unsigned short u16;
typedef __attribute__((ext_vector_type(8))) short bf16x8;
typedef __attribute__((ext_vector_type(4))) float f32x4;
typedef __attribute__((ext_vector_type(4))) u32 u32x4;
typedef __attribute__((ext_vector_type(2))) u32 u32x2;

__device__ __forceinline__ u16 f2bf(float f) {
  u32 u = __builtin_bit_cast(u32, f);
  u32 r = (u + 0x7FFFu + ((u >> 16) & 1u)) >> 16;   // RNE
  return (u16)r;
}

// ------------------------------------------------------------------
// Kernel 0: weight re-layouts (tiny).
// ------------------------------------------------------------------
__global__ __launch_bounds__(256) void prep_weights(
    const float* __restrict__ w_comp, const float* __restrict__ w_enc,
    float* __restrict__ wct, u16* __restrict__ wfrag) {
  int idx = blockIdx.x * 256 + threadIdx.x;
  if (idx < 50 * 14 * 64) {
    int lane = idx & 63;
    int mt   = (idx >> 6) % 14;
    int ks   = idx / (14 * 64);
    int o    = mt * 16 + (lane & 15);
    int tap  = ks >> 1, s = ks & 1;
    int ky   = tap / 5, kx = tap % 5;
    int cb   = s * 32 + (lane >> 4) * 8;
    u32 pk[4];
    #pragma unroll
    for (int p = 0; p < 4; ++p) {
      u16 lo = 0, hi = 0;
      if (o < OE_) {
        lo = f2bf(w_enc[((o * CC_ + cb + 2 * p) * 5 + ky) * 5 + kx]);
        hi = f2bf(w_enc[((o * CC_ + cb + 2 * p + 1) * 5 + ky) * 5 + kx]);
      }
      pk[p] = (u32)lo | ((u32)hi << 16);
    }
    *reinterpret_cast<u32x4*>(wfrag + (size_t)idx * 8) =
        *reinterpret_cast<u32x4*>(pk);
  }
  if (idx < C_ * CC_) {
    int cc = idx / C_, c = idx % C_;
    wct[c * CC_ + cc] = w_comp[cc * C_ + c];
  }
}

// ------------------------------------------------------------------
// Kernel 1: 1x1 compressor — also emits xbf[b][h][w][c] bf16
// channels-last (reuses the xs LDS reads it already does).
// ------------------------------------------------------------------
__global__ __launch_bounds__(256) void compress_k(
    const float* __restrict__ x, const float* __restrict__ wct,
    const float* __restrict__ b_comp, u16* __restrict__ comp,
    u16* __restrict__ xbf) {
  __shared__ float xs[C_ * 20];
  int t   = threadIdx.x;
  int gid = blockIdx.x;
  int wq  = gid & 3;
  int bh  = gid >> 2;
  int b = bh >> 6, h = bh & 63;
  int w0 = wq * 16;

  const float* xrow = x + (size_t)b * C_ * H_ * W_ + (size_t)h * W_ + w0;
  for (int i = t; i < 1024; i += 256) {
    int c = i >> 2, q = i & 3;
    f32x4 v = *reinterpret_cast<const f32x4*>(xrow + (size_t)c * H_ * W_ + q * 4);
    *reinterpret_cast<f32x4*>(xs + c * 20 + q * 4) = v;
  }
  __syncthreads();

  int w = t & 15, cq = t >> 4;   // cq 0..15 -> 4 cc each
  float acc[4] = {0.f, 0.f, 0.f, 0.f};
  for (int c = 0; c < C_; ++c) {
    float xv = xs[c * 20 + w];
    const float* wr = wct + c * CC_ + cq * 4;
    #pragma unroll
    for (int i = 0; i < 4; ++i) acc[i] = fmaf(xv, wr[i], acc[i]);
  }
  u32 pk[2];
  #pragma unroll
  for (int p = 0; p < 2; ++p) {
    u16 lo = f2bf(acc[2 * p]     + b_comp[cq * 4 + 2 * p]);
    u16 hi = f2bf(acc[2 * p + 1] + b_comp[cq * 4 + 2 * p + 1]);
    pk[p] = (u32)lo | ((u32)hi << 16);
  }
  *reinterpret_cast<u32x2*>(comp + ((size_t)bh * 64 + w0 + w) * CC_ + cq * 4) =
      *reinterpret_cast<u32x2*>(pk);

  // ---- xbf: thread (w,cq) packs channels cq*16..cq*16+15 ----
  {
    u32 px[8];
    #pragma unroll
    for (int i = 0; i < 8; ++i) {
      u16 lo = f2bf(xs[(cq * 16 + 2 * i) * 20 + w]);
      u16 hi = f2bf(xs[(cq * 16 + 2 * i + 1) * 20 + w]);
      px[i] = (u32)lo | ((u32)hi << 16);
    }
    u16* dst = xbf + ((size_t)bh * 64 + w0 + w) * C_ + cq * 16;
    reinterpret_cast<u32x4*>(dst)[0] = *reinterpret_cast<u32x4*>(px);
    reinterpret_cast<u32x4*>(dst)[1] = *reinterpret_cast<u32x4*>(px + 4);
  }
}

// ------------------------------------------------------------------
// Kernel 2: encoder MFMA GEMM v5 — N-split, barrier-free K-loop
// (R8 version: proven fastest enc structure).
// ------------------------------------------------------------------
#define ELG_ 32256   // 224*36*4

__device__ __forceinline__ void enc_lda(
    bf16x8 (&a)[4], const u16* __restrict__ wfrag,
    int ks, int mtbase, int mtcnt, int lane) {
  #pragma unroll
  for (int mm = 0; mm < 4; ++mm)
    if (mm < mtcnt)
      a[mm] = *reinterpret_cast<const bf16x8*>(
          wfrag + (((size_t)ks * 14 + mtbase + mm) * 64 + lane) * 8);
}

__device__ __forceinline__ void enc_step(
    int ks, const char* lds, const bf16x8 (&a)[4], f32x4 (&acc)[4][2],
    int nlane, int kq, int mtcnt) {
  int tap = ks >> 1, s = ks & 1;
  int ky = tap / 5, kx = tap % 5;
  bf16x8 bf[2];
  #pragma unroll
  for (int nt = 0; nt < 2; ++nt) {
    int col = nt * 16 + nlane + kx;
    int byte = (((ky * 36 + col) * 64 + s * 32 + kq * 8) * 2) ^ ((col & 7) << 4);
    bf[nt] = *reinterpret_cast<const bf16x8*>(lds + byte);
  }
  #pragma unroll
  for (int mm = 0; mm < 4; ++mm) {
    if (mm < mtcnt) {
      #pragma unroll
      for (int nt = 0; nt < 2; ++nt)
        acc[mm][nt] = __builtin_amdgcn_mfma_f32_16x16x32_bf16(
            a[mm], bf[nt], acc[mm][nt], 0, 0, 0);
    }
  }
}

__global__ __launch_bounds__(256) void enc_mfma_k(
    const u16* __restrict__ comp, const u16* __restrict__ wfrag,
    const float* __restrict__ b_enc, float* __restrict__ smax) {
  __shared__ __align__(16) char lds[ELG_];

  int t   = threadIdx.x;
  int bid = blockIdx.x;
  int swz = (bid & 7) * 64 + (bid >> 3);   // 512 blocks, bijective
  int wh  = swz & 1;
  int bh  = swz >> 1;
  int b = bh >> 6, h = bh & 63;
  int w0 = wh * 32;

  // ---- stage B tile: 5 rows x 36 cols x 64 ch, XOR-swizzled ----
  {
    const u16* cbse = comp + (size_t)b * H_ * W_ * CC_;
    for (int i = t; i < 1440; i += 256) {
      int q = i & 7, colr = i >> 3;
      int col = colr % 36, r = colr / 36;
      int hh = h - 2 + r, gw = w0 - 2 + col;
      u32x4 v = {0, 0, 0, 0};
      if ((unsigned)hh < H_ && (unsigned)gw < W_)
        v = *reinterpret_cast<const u32x4*>(cbse + ((size_t)hh * W_ + gw) * CC_ + q * 8);
      int byte = ((r * 36 + col) * 128 + q * 16) ^ ((col & 7) << 4);
      *reinterpret_cast<u32x4*>(lds + byte) = v;
    }
  }
  __syncthreads();   // B ready; no further barriers in K-loop

  int wv    = __builtin_amdgcn_readfirstlane(t >> 6);
  int lane  = t & 63;
  int nlane = lane & 15, kq = lane >> 4;
  int mtbase = (wv < 2) ? wv * 4 : 3 * wv + 2;   // {0,4,8,11}
  int mtcnt  = (wv < 2) ? 4 : 3;

  f32x4 acc[4][2];
  #pragma unroll
  for (int mm = 0; mm < 4; ++mm)
    #pragma unroll
    for (int nt = 0; nt < 2; ++nt) acc[mm][nt] = (f32x4){0.f, 0.f, 0.f, 0.f};

  bf16x8 aA[4], aB[4];
  enc_lda(aA, wfrag, 0, mtbase, mtcnt, lane);
  enc_lda(aB, wfrag, 1, mtbase, mtcnt, lane);
  for (int ks = 0; ks + 2 < 50; ks += 2) {
    enc_step(ks, lds, aA, acc, nlane, kq, mtcnt);
    enc_lda(aA, wfrag, ks + 2, mtbase, mtcnt, lane);
    enc_step(ks + 1, lds, aB, acc, nlane, kq, mtcnt);
    enc_lda(aB, wfrag, ks + 3, mtbase, mtcnt, lane);
  }
  enc_step(48, lds, aA, acc, nlane, kq, mtcnt);
  enc_step(49, lds, aB, acc, nlane, kq, mtcnt);

  // ---- epilogue: logits -> LDS [224][36] f32, fused softmax ----
  __syncthreads();
  float* lg = (float*)lds;
  #pragma unroll
  for (int mm = 0; mm < 4; ++mm) {
    if (mm < mtcnt) {
      #pragma unroll
      for (int nt = 0; nt < 2; ++nt) {
        #pragma unroll
        for (int r = 0; r < 4; ++r) {
          int m  = (mtbase + mm) * 16 + kq * 4 + r;
          int px = nt * 16 + nlane;
          lg[m * 36 + px] = acc[mm][nt][r] + (m < OE_ ? b_enc[m] : 0.f);
        }
      }
    }
  }
  __syncthreads();

  if (t < 128) {
    int px = t & 31, rr = t >> 5;
    float v[49];
    float mx = -1e30f;
    #pragma unroll
    for (int n = 0; n < 49; ++n) {
      v[n] = lg[(4 * n + rr) * 36 + px];
      mx = fmaxf(mx, v[n]);
    }
    float sum = 0.f;
    #pragma unroll
    for (int n = 0; n < 49; ++n) { v[n] = __expf(v[n] - mx); sum += v[n]; }
    float inv = 1.f / sum;
    float* so = smax + ((size_t)bh * 64 + w0 + px) * OE_;
    #pragma unroll
    for (int n = 0; n < 49; ++n) so[n * 4 + rr] = v[n] * inv;   // [n][r]
  }
}

// ------------------------------------------------------------------
// Kernel 3: CARAFE v11 — LDS-instruction-minimized (>=16 FMA per LDS
// read).  Block = (b, 2 h-rows, 8 w, 256 ch).  xs = bf16 [8 rows]
// [14 j][256 c], slot-XOR swizzled (slot ^ (j&7)) -> exact b128 floor,
// no extra conflicts.  ssm [2][8][200] f32 (stride 200 = broadcast-
// clean).  Thread = (w, 8 ch): per tap 1 xv b128 (8 ch bf16) + sv
// amortized; row-major loop shares xv across both h outputs:
// 154 compute b128/thread (v10: 784).
// ------------------------------------------------------------------
__global__ __launch_bounds__(256) void carafe_k(
    const u16* __restrict__ xbf, const float* __restrict__ smax,
    float* __restrict__ out) {
  __shared__ __align__(16) u16 xs[8 * 14 * 256];     // 57,344 B
  __shared__ __align__(16) float ssm[2 * 8 * 200];   // 12,800 B
  int t   = threadIdx.x;
  int bid = blockIdx.x;
  int swz = (bid & 7) * 128 + (bid >> 3);   // 1024 blocks, bijective
  int wq  = swz & 7;
  int hp  = (swz >> 3) & 31;
  int b   = swz >> 8;
  int w0 = wq * 8, h0 = hp * 2;

  // ---- stage xs: 8 rows x 14 j x 32 slots (8 ch each), swizzled ----
  {
    const u16* xb = xbf + (size_t)b * H_ * W_ * C_;
    #pragma unroll
    for (int it = 0; it < 14; ++it) {
      int idx  = it * 256 + t;          // 0..3583
      int slot = idx & 31;
      int j    = (idx >> 5) % 14;
      int row  = idx / (32 * 14);
      int gh = h0 - 3 + row, gw = w0 - 3 + j;
      u32x4 v = {0, 0, 0, 0};
      if ((unsigned)gh < H_ && (unsigned)gw < W_)
        v = *reinterpret_cast<const u32x4*>(xb + ((gh * W_ + gw) * C_ + slot * 8));
      int dst = row * 3584 + j * 256 + ((slot ^ (j & 7)) * 8);   // u16 units
      *reinterpret_cast<u32x4*>(xs + dst) = v;
    }
  }
  // ---- stage ssm: 2 h x 8 w x 49 f32x4 ----
  for (int idx = t; idx < 784; idx += 256) {
    int n4 = idx % 49;
    int wv = (idx / 49) & 7;
    int hs = idx / 392;
    const float* sp = smax +
        ((size_t)((b * H_ + h0 + hs) * W_) + w0 + wv) * OE_ + n4 * 4;
    f32x4 v = *reinterpret_cast<const f32x4*>(sp);
    *reinterpret_cast<f32x4*>(ssm + (hs * 8 + wv) * 200 + n4 * 4) = v;
  }
  __syncthreads();

  int w = t & 7, grp = t >> 3;   // grp 0..31 -> 8 channels
  const float* s0base = ssm + w * 200;          // hs = 0
  const float* s1base = ssm + (8 + w) * 200;    // hs = 1
  f32x4 acc0[8], acc1[8];
  #pragma unroll
  for (int ci = 0; ci < 8; ++ci) {
    acc0[ci] = (f32x4){0.f, 0.f, 0.f, 0.f};
    acc1[ci] = (f32x4){0.f, 0.f, 0.f, 0.f};
  }

  #pragma unroll
  for (int row = 0; row < 8; ++row) {
    #pragma unroll
    for (int dx = 0; dx < 7; ++dx) {
      int j = w + dx;
      u32x4 u = *reinterpret_cast<const u32x4*>(
          xs + row * 3584 + j * 256 + ((grp ^ (j & 7)) * 8));
      float xf[8];
      #pragma unroll
      for (int k = 0; k < 4; ++k) {
        xf[2 * k]     = __builtin_bit_cast(float, u[k] << 16);
        xf[2 * k + 1] = __builtin_bit_cast(float, u[k] & 0xffff0000u);
      }
      if (row < 7) {   // contributes to hs=0, dy=row
        f32x4 s0 = *reinterpret_cast<const f32x4*>(s0base + (row * 7 + dx) * 4);
        #pragma unroll
        for (int ci = 0; ci < 8; ++ci) {
          acc0[ci][0] = fmaf(xf[ci], s0[0], acc0[ci][0]);
          acc0[ci][1] = fmaf(xf[ci], s0[1], acc0[ci][1]);
          acc0[ci][2] = fmaf(xf[ci], s0[2], acc0[ci][2]);
          acc0[ci][3] = fmaf(xf[ci], s0[3], acc0[ci][3]);
        }
      }
      if (row >= 1) {  // contributes to hs=1, dy=row-1
        f32x4 s1 = *reinterpret_cast<const f32x4*>(s1base + ((row - 1) * 7 + dx) * 4);
        #pragma unroll
        for (int ci = 0; ci < 8; ++ci) {
          acc1[ci][0] = fmaf(xf[ci], s1[0], acc1[ci][0]);
          acc1[ci][1] = fmaf(xf[ci], s1[1], acc1[ci][1]);
          acc1[ci][2] = fmaf(xf[ci], s1[2], acc1[ci][2]);
          acc1[ci][3] = fmaf(xf[ci], s1[3], acc1[ci][3]);
        }
      }
    }
  }

  #pragma unroll
  for (int ci = 0; ci < 8; ++ci) {
    int c = grp * 8 + ci;
    float* base = out + ((size_t)(b * C_ + c) * OH_ + 2 * h0) * OW_ + 2 * (w0 + w);
    *reinterpret_cast<float2*>(base)            = make_float2(acc0[ci][0], acc0[ci][1]);
    *reinterpret_cast<float2*>(base + OW_)      = make_float2(acc0[ci][2], acc0[ci][3]);
    *reinterpret_cast<float2*>(base + 2 * OW_)  = make_float2(acc1[ci][0], acc1[ci][1]);
    *reinterpret_cast<float2*>(base + 3 * OW_)  = make_float2(acc1[ci][2], acc1[ci][3]);
  }
}

// ------------------------------------------------------------------
extern "C" void kernel_launch(void* const* d_in, const int* in_sizes, int n_in,
                              void* d_out, int out_size, void* d_ws, size_t ws_size,
                              hipStream_t stream) {
  const float* x      = (const float*)d_in[0];
  const float* w_comp = (const float*)d_in[1];
  const float* b_comp = (const float*)d_in[2];
  const float* w_enc  = (const float*)d_in[3];
  const float* b_enc  = (const float*)d_in[4];
  float* out = (float*)d_out;

  float* ws = (float*)d_ws;
  float* smax = ws;                             // 3,211,264 f32
  float* wct  = ws + 3211264;                   //    16,384 f32
  u16* wfrag  = (u16*)(wct + 16384);            //   358,400 bf16
  u16* comp   = wfrag + 358400;                 // 1,048,576 bf16
  u16* xbf    = comp + 1048576;                 // 4,194,304 bf16 (~24.1MB total)

  prep_weights<<<175, 256, 0, stream>>>(w_comp, w_enc, wct, wfrag);
  compress_k<<<B_ * H_ * 4, 256, 0, stream>>>(x, wct, b_comp, comp, xbf);
  enc_mfma_k<<<512, 256, 0, stream>>>(comp, wfrag, b_enc, smax);
  carafe_k<<<1024, 256, 0, stream>>>(xbf, smax, out);
}